// Round 7
// baseline (129.015 us; speedup 1.0000x reference)
//
#include <hip/hip_runtime.h>

typedef __attribute__((ext_vector_type(4))) int int4v;

constexpr int Mdim = 32768;   // 8*4096
constexpr int Kdim = 1024;
constexpr int Ndim = 1024;
constexpr float FEPS = 1e-8f;

// ---------------- ws layout (bytes) ----------------
// 0      : float scalars[8]  {gamma_w, gamma_b, scale, sg, qs, inv_scale}
// 1024   : float partials[256]   (|W| partial sums)
// 4096   : unsigned pmax[2048]   (per-block |x| max bits)
// 16384  : float bq[1024]
// 32768  : int8 wq (1 MB)  -- TILED: tile t=(nb*16+kt) is 1KB; byte l*16 of tile t
//                             holds W[nb*16 + (l&15)][kt*64 + (l>>4)*16 .. +15]
constexpr size_t WQ_OFF = 32768;
constexpr size_t WS_NEED = WQ_OFF + (size_t)Ndim * Kdim;

// ---------------- pass 1 (merged): |x| absmax partials + |W| sum partials ----
// blocks [0,2048): absmax of x -> pmax[b]; blocks [2048,2304): |W| sums -> partials[b-2048]
__global__ void k_pre(const uint4* __restrict__ xv, const float4* __restrict__ wv,
                      unsigned* __restrict__ pmax, float* __restrict__ partials) {
  const int tid = threadIdx.x;
  if (blockIdx.x < 2048) {
    int i0 = blockIdx.x * 256 + tid;
    const int stride = 2048 * 256;
    const int n4 = Mdim * Kdim / 4;
    unsigned m = 0u;
    for (int i = i0; i < n4; i += stride) {
      uint4 v = xv[i];
      m = max(m, v.x & 0x7fffffffu);
      m = max(m, v.y & 0x7fffffffu);
      m = max(m, v.z & 0x7fffffffu);
      m = max(m, v.w & 0x7fffffffu);
    }
    #pragma unroll
    for (int off = 32; off > 0; off >>= 1)
      m = max(m, (unsigned)__shfl_down((int)m, off, 64));
    __shared__ unsigned red[4];
    if ((tid & 63) == 0) red[tid >> 6] = m;
    __syncthreads();
    if (tid == 0)
      pmax[blockIdx.x] = max(max(red[0], red[1]), max(red[2], red[3]));
  } else {
    int wb = blockIdx.x - 2048;
    float s = 0.f;
    const int stride = 256 * 256;
    const int n4 = Ndim * Kdim / 4;
    for (int i = wb * 256 + tid; i < n4; i += stride) {
      float4 v = wv[i];
      s += fabsf(v.x) + fabsf(v.y) + fabsf(v.z) + fabsf(v.w);
    }
    __shared__ float red[256];
    red[tid] = s;
    __syncthreads();
    for (int h = 128; h > 0; h >>= 1) {
      if (tid < h) red[tid] += red[tid + h];
      __syncthreads();
    }
    if (tid == 0) partials[wb] = red[0];
  }
}

// ---------------- pass 2: scalars + bias quant + W quant (256 blocks) --------
__global__ void k_finalize2(const float* __restrict__ bias, const float* __restrict__ w,
                            const float* __restrict__ partials, const unsigned* __restrict__ pmax,
                            float* __restrict__ scalars, float* __restrict__ bq,
                            unsigned char* __restrict__ wq) {
  __shared__ float red[256];
  const int t = threadIdx.x;
  const int b = blockIdx.x;

  // local gamma_w from the 256 fixed partials
  red[t] = partials[t];
  __syncthreads();
  for (int h = 128; h > 0; h >>= 1) {
    if (t < h) red[t] += red[t + h];
    __syncthreads();
  }
  const float gw = red[0] / (1024.0f * 1024.0f);
  __syncthreads();
  const float inv_g = gw + FEPS;

  // quantize 4 W tiles: tile = b*4 + (t>>6); coalesced read, permuted write
  {
    const int tile = b * 4 + (t >> 6);   // 0..1023
    const int nb = tile >> 4;
    const int kt = tile & 15;
    const int l = t & 63;
    const float4* src = (const float4*)(w + (size_t)(nb * 16 + (l >> 2)) * Kdim + kt * 64 + (l & 3) * 16);
    unsigned o[4];
    #pragma unroll
    for (int v = 0; v < 4; ++v) {
      float4 f = src[v];
      int a  = (int)rintf(fminf(fmaxf(f.x / inv_g, -1.f), 1.f));
      int bb = (int)rintf(fminf(fmaxf(f.y / inv_g, -1.f), 1.f));
      int cc = (int)rintf(fminf(fmaxf(f.z / inv_g, -1.f), 1.f));
      int dd = (int)rintf(fminf(fmaxf(f.w / inv_g, -1.f), 1.f));
      o[v] = (unsigned)(a & 0xff) | ((unsigned)(bb & 0xff) << 8) |
             ((unsigned)(cc & 0xff) << 16) | ((unsigned)(dd & 0xff) << 24);
    }
    uint4 pk; pk.x = o[0]; pk.y = o[1]; pk.z = o[2]; pk.w = o[3];
    const int lp = (l >> 2) | ((l & 3) << 4);   // fragment lane
    *(uint4*)(wq + (size_t)tile * 1024 + lp * 16) = pk;
  }

  if (b != 0) return;

  // block 0: absmax reduce + scalars + bq
  __shared__ unsigned redu[256];
  __shared__ float sh_gb;
  unsigned m = 0u;
  #pragma unroll
  for (int i = 0; i < 8; ++i) m = max(m, pmax[t + 256 * i]);
  redu[t] = m;
  float s = fabsf(bias[t]) + fabsf(bias[t + 256]) + fabsf(bias[t + 512]) + fabsf(bias[t + 768]);
  red[t] = s;
  __syncthreads();
  for (int h = 128; h > 0; h >>= 1) {
    if (t < h) {
      red[t] += red[t + h];
      redu[t] = max(redu[t], redu[t + h]);
    }
    __syncthreads();
  }
  if (t == 0) {
    float gb = red[0] / 1024.0f;
    float maxval = __uint_as_float(redu[0]);
    float v = maxval / 127.0f + FEPS;
    int e = (int)((__float_as_uint(v) >> 23) & 0xff) - 127;
    float scale = ldexpf(1.0f, e);
    scalars[0] = gw;
    scalars[1] = gb;
    scalars[2] = scale;
    scalars[3] = scale * gw;       // epilogue multiplier
    scalars[4] = 127.0f * scale;   // clip bound (exact)
    scalars[5] = ldexpf(1.0f, -e); // inv_scale (exact power of 2)
    sh_gb = gb;
  }
  __syncthreads();
  float gb = sh_gb;
  for (int i = t; i < 1024; i += 256) {
    float q = rintf(bias[i] / (gb + FEPS));
    q = fminf(fmaxf(q, -1.0f), 1.0f);
    bq[i] = q * gb;
  }
}

// ---------------- pass 3: fused quant + int8 MFMA GEMM ----------------------
// One block per mtile (128 rows), 16 waves. Phase A: quantize this block's
// 128x1024 fp32 x-panel into LDS (fragment-tiled int8, 128 KB), one barrier.
// Phase B: barrier-free K-loop; A-frags from LDS (linear ds_read_b128,
// conflict-free), B-frags direct global->VGPR from L2-resident tiled wq.
// Wave grid 2x8: wave (wr=wv>>3, wc=wv&7) owns rows wr*64+[0,64), cols
// wc*64 within each 512-col half; np=0..1 covers the 1024 output cols.
// 64x64 per wave = 16 MFMA per 4 B-loads -> wq L2 traffic 2 MB/block.
__launch_bounds__(1024)
__global__ void k_megagemm(const float* __restrict__ x, const unsigned char* __restrict__ wq,
                           const float* __restrict__ scalars, const float* __restrict__ bq,
                           float* __restrict__ out) {
  __shared__ __align__(16) unsigned char Alds[131072];   // 128 tiles x 1KB

  const int tid = threadIdx.x;
  const int lane = tid & 63;
  const int wv = tid >> 6;          // 0..15
  const int mtile = blockIdx.x;     // 0..255
  const float qs = scalars[4], inv = scalars[5];

  // ---- Phase A: quantize 8 tiles per wave into LDS ----
  #pragma unroll
  for (int i = 0; i < 8; ++i) {
    const int tile = wv * 8 + i;    // 0..127
    const int mb = tile >> 4;
    const int kt = tile & 15;
    const float4* src = (const float4*)(x + (size_t)(mtile * 128 + mb * 16 + (lane >> 2)) * Kdim
                                          + kt * 64 + (lane & 3) * 16);
    unsigned o[4];
    #pragma unroll
    for (int v = 0; v < 4; ++v) {
      float4 f = src[v];
      int a = (int)rintf(fminf(fmaxf(f.x, -qs), qs) * inv);
      int b = (int)rintf(fminf(fmaxf(f.y, -qs), qs) * inv);
      int c = (int)rintf(fminf(fmaxf(f.z, -qs), qs) * inv);
      int d = (int)rintf(fminf(fmaxf(f.w, -qs), qs) * inv);
      o[v] = (unsigned)(a & 0xff) | ((unsigned)(b & 0xff) << 8) |
             ((unsigned)(c & 0xff) << 16) | ((unsigned)(d & 0xff) << 24);
    }
    uint4 pk; pk.x = o[0]; pk.y = o[1]; pk.z = o[2]; pk.w = o[3];
    const int lp = (lane >> 2) | ((lane & 3) << 4);   // fragment lane
    *(uint4*)(Alds + (size_t)tile * 1024 + lp * 16) = pk;
  }
  __syncthreads();   // the only barrier; Alds is read-only below

  // ---- Phase B: GEMM, 64x64 per wave ----
  const int wr = wv >> 3;           // 0..1 : rows wr*64
  const int wc = wv & 7;            // 0..7 : cols wc*64 (within 512-wide half)
  const float sg = scalars[3];
  const unsigned char* Aw = Alds + (size_t)(wr * 4) * 16 * 1024 + lane * 16;

  #pragma unroll
  for (int np = 0; np < 2; ++np) {
    int4v acc[4][4];
    #pragma unroll
    for (int i = 0; i < 4; ++i)
      #pragma unroll
      for (int j = 0; j < 4; ++j)
        acc[i][j] = (int4v){0, 0, 0, 0};

    const unsigned char* Bb = wq + ((size_t)(np * 32 + wc * 4) * 16) * 1024 + lane * 16;

    #pragma unroll
    for (int kt = 0; kt < 16; ++kt) {
      int4v b0 = *(const int4v*)(Bb + (size_t)(0 * 16 + kt) * 1024);
      int4v b1 = *(const int4v*)(Bb + (size_t)(1 * 16 + kt) * 1024);
      int4v b2 = *(const int4v*)(Bb + (size_t)(2 * 16 + kt) * 1024);
      int4v b3 = *(const int4v*)(Bb + (size_t)(3 * 16 + kt) * 1024);
      int4v a0 = *(const int4v*)(Aw + (size_t)(0 * 16 + kt) * 1024);
      int4v a1 = *(const int4v*)(Aw + (size_t)(1 * 16 + kt) * 1024);
      int4v a2 = *(const int4v*)(Aw + (size_t)(2 * 16 + kt) * 1024);
      int4v a3 = *(const int4v*)(Aw + (size_t)(3 * 16 + kt) * 1024);
      acc[0][0] = __builtin_amdgcn_mfma_i32_16x16x64_i8(a0, b0, acc[0][0], 0, 0, 0);
      acc[0][1] = __builtin_amdgcn_mfma_i32_16x16x64_i8(a0, b1, acc[0][1], 0, 0, 0);
      acc[0][2] = __builtin_amdgcn_mfma_i32_16x16x64_i8(a0, b2, acc[0][2], 0, 0, 0);
      acc[0][3] = __builtin_amdgcn_mfma_i32_16x16x64_i8(a0, b3, acc[0][3], 0, 0, 0);
      acc[1][0] = __builtin_amdgcn_mfma_i32_16x16x64_i8(a1, b0, acc[1][0], 0, 0, 0);
      acc[1][1] = __builtin_amdgcn_mfma_i32_16x16x64_i8(a1, b1, acc[1][1], 0, 0, 0);
      acc[1][2] = __builtin_amdgcn_mfma_i32_16x16x64_i8(a1, b2, acc[1][2], 0, 0, 0);
      acc[1][3] = __builtin_amdgcn_mfma_i32_16x16x64_i8(a1, b3, acc[1][3], 0, 0, 0);
      acc[2][0] = __builtin_amdgcn_mfma_i32_16x16x64_i8(a2, b0, acc[2][0], 0, 0, 0);
      acc[2][1] = __builtin_amdgcn_mfma_i32_16x16x64_i8(a2, b1, acc[2][1], 0, 0, 0);
      acc[2][2] = __builtin_amdgcn_mfma_i32_16x16x64_i8(a2, b2, acc[2][2], 0, 0, 0);
      acc[2][3] = __builtin_amdgcn_mfma_i32_16x16x64_i8(a2, b3, acc[2][3], 0, 0, 0);
      acc[3][0] = __builtin_amdgcn_mfma_i32_16x16x64_i8(a3, b0, acc[3][0], 0, 0, 0);
      acc[3][1] = __builtin_amdgcn_mfma_i32_16x16x64_i8(a3, b1, acc[3][1], 0, 0, 0);
      acc[3][2] = __builtin_amdgcn_mfma_i32_16x16x64_i8(a3, b2, acc[3][2], 0, 0, 0);
      acc[3][3] = __builtin_amdgcn_mfma_i32_16x16x64_i8(a3, b3, acc[3][3], 0, 0, 0);
    }

    // epilogue for this column half (writes overlap next half's compute)
    #pragma unroll
    for (int ni = 0; ni < 4; ++ni) {
      const int col = np * 512 + wc * 64 + ni * 16 + (lane & 15);
      const float bb = bq[col];
      #pragma unroll
      for (int mi = 0; mi < 4; ++mi) {
        const int rowb = mtile * 128 + wr * 64 + mi * 16 + (lane >> 4) * 4;
        #pragma unroll
        for (int r = 0; r < 4; ++r)
          out[(size_t)(rowb + r) * Ndim + col] = (float)acc[mi][ni][r] * sg + bb;
      }
    }
  }
}

extern "C" void kernel_launch(void* const* d_in, const int* in_sizes, int n_in,
                              void* d_out, int out_size, void* d_ws, size_t ws_size,
                              hipStream_t stream) {
  const float* x = (const float*)d_in[0];
  const float* weight = (const float*)d_in[1];
  const float* bias = (const float*)d_in[2];
  float* out = (float*)d_out;

  if (ws_size < WS_NEED) return;

  char* ws = (char*)d_ws;
  float* scalars = (float*)ws;
  float* partials = (float*)(ws + 1024);
  unsigned* pmax = (unsigned*)(ws + 4096);
  float* bq = (float*)(ws + 16384);
  unsigned char* wq = (unsigned char*)(ws + WQ_OFF);

  k_pre<<<2304, 256, 0, stream>>>((const uint4*)x, (const float4*)weight, pmax, partials);
  k_finalize2<<<256, 256, 0, stream>>>(bias, weight, partials, pmax, scalars, bq, wq);
  k_megagemm<<<256, 1024, 0, stream>>>(x, wq, scalars, bq, out);
}

// Round 8
// 111.353 us; speedup vs baseline: 1.1586x; 1.1586x over previous
//
#include <hip/hip_runtime.h>

typedef __attribute__((ext_vector_type(4))) int int4v;

constexpr int Mdim = 32768;   // 8*4096
constexpr int Kdim = 1024;
constexpr int Ndim = 1024;
constexpr float FEPS = 1e-8f;

// ---------------- ws layout (bytes) ----------------
// 0      : float scalars[8]  {gamma_w, gamma_b, scale, sg, qs, inv_scale}
// 1024   : float partials[256]   (|W| partial sums)
// 4096   : unsigned pmax[2048]   (per-block |x| max bits)
// 16384  : float bq[1024]
// 32768  : int8 wq (1 MB)  -- TILED: tile t=(nb*16+kt) is 1KB; byte l*16 of tile t
//                             holds W[nb*16 + (l&15)][kt*64 + (l>>4)*16 .. +15]
constexpr size_t WQ_OFF = 32768;
constexpr size_t WS_NEED = WQ_OFF + (size_t)Ndim * Kdim;

// ---------------- pass 1 (merged): |x| absmax partials + |W| sum partials ----
// blocks [0,2048): absmax of x -> pmax[b]; blocks [2048,2304): |W| sums -> partials[b-2048]
__global__ void k_pre(const uint4* __restrict__ xv, const float4* __restrict__ wv,
                      unsigned* __restrict__ pmax, float* __restrict__ partials) {
  const int tid = threadIdx.x;
  if (blockIdx.x < 2048) {
    int i0 = blockIdx.x * 256 + tid;
    const int stride = 2048 * 256;
    const int n4 = Mdim * Kdim / 4;
    unsigned m = 0u;
    for (int i = i0; i < n4; i += stride) {
      uint4 v = xv[i];
      m = max(m, v.x & 0x7fffffffu);
      m = max(m, v.y & 0x7fffffffu);
      m = max(m, v.z & 0x7fffffffu);
      m = max(m, v.w & 0x7fffffffu);
    }
    #pragma unroll
    for (int off = 32; off > 0; off >>= 1)
      m = max(m, (unsigned)__shfl_down((int)m, off, 64));
    __shared__ unsigned red[4];
    if ((tid & 63) == 0) red[tid >> 6] = m;
    __syncthreads();
    if (tid == 0)
      pmax[blockIdx.x] = max(max(red[0], red[1]), max(red[2], red[3]));
  } else {
    int wb = blockIdx.x - 2048;
    float s = 0.f;
    const int stride = 256 * 256;
    const int n4 = Ndim * Kdim / 4;
    for (int i = wb * 256 + tid; i < n4; i += stride) {
      float4 v = wv[i];
      s += fabsf(v.x) + fabsf(v.y) + fabsf(v.z) + fabsf(v.w);
    }
    __shared__ float red[256];
    red[tid] = s;
    __syncthreads();
    for (int h = 128; h > 0; h >>= 1) {
      if (tid < h) red[tid] += red[tid + h];
      __syncthreads();
    }
    if (tid == 0) partials[wb] = red[0];
  }
}

// ---------------- pass 2: scalars + bias quant + W quant (256 blocks) --------
__global__ void k_finalize2(const float* __restrict__ bias, const float* __restrict__ w,
                            const float* __restrict__ partials, const unsigned* __restrict__ pmax,
                            float* __restrict__ scalars, float* __restrict__ bq,
                            unsigned char* __restrict__ wq) {
  __shared__ float red[256];
  const int t = threadIdx.x;
  const int b = blockIdx.x;

  // local gamma_w from the 256 fixed partials
  red[t] = partials[t];
  __syncthreads();
  for (int h = 128; h > 0; h >>= 1) {
    if (t < h) red[t] += red[t + h];
    __syncthreads();
  }
  const float gw = red[0] / (1024.0f * 1024.0f);
  __syncthreads();
  const float inv_g = gw + FEPS;

  // quantize 4 W tiles: tile = b*4 + (t>>6); coalesced read, permuted write
  {
    const int tile = b * 4 + (t >> 6);   // 0..1023
    const int nb = tile >> 4;
    const int kt = tile & 15;
    const int l = t & 63;
    const float4* src = (const float4*)(w + (size_t)(nb * 16 + (l >> 2)) * Kdim + kt * 64 + (l & 3) * 16);
    unsigned o[4];
    #pragma unroll
    for (int v = 0; v < 4; ++v) {
      float4 f = src[v];
      int a  = (int)rintf(fminf(fmaxf(f.x / inv_g, -1.f), 1.f));
      int bb = (int)rintf(fminf(fmaxf(f.y / inv_g, -1.f), 1.f));
      int cc = (int)rintf(fminf(fmaxf(f.z / inv_g, -1.f), 1.f));
      int dd = (int)rintf(fminf(fmaxf(f.w / inv_g, -1.f), 1.f));
      o[v] = (unsigned)(a & 0xff) | ((unsigned)(bb & 0xff) << 8) |
             ((unsigned)(cc & 0xff) << 16) | ((unsigned)(dd & 0xff) << 24);
    }
    uint4 pk; pk.x = o[0]; pk.y = o[1]; pk.z = o[2]; pk.w = o[3];
    const int lp = (l >> 2) | ((l & 3) << 4);   // fragment lane
    *(uint4*)(wq + (size_t)tile * 1024 + lp * 16) = pk;
  }

  if (b != 0) return;

  // block 0: absmax reduce + scalars + bq
  __shared__ unsigned redu[256];
  __shared__ float sh_gb;
  unsigned m = 0u;
  #pragma unroll
  for (int i = 0; i < 8; ++i) m = max(m, pmax[t + 256 * i]);
  redu[t] = m;
  float s = fabsf(bias[t]) + fabsf(bias[t + 256]) + fabsf(bias[t + 512]) + fabsf(bias[t + 768]);
  red[t] = s;
  __syncthreads();
  for (int h = 128; h > 0; h >>= 1) {
    if (t < h) {
      red[t] += red[t + h];
      redu[t] = max(redu[t], redu[t + h]);
    }
    __syncthreads();
  }
  if (t == 0) {
    float gb = red[0] / 1024.0f;
    float maxval = __uint_as_float(redu[0]);
    float v = maxval / 127.0f + FEPS;
    int e = (int)((__float_as_uint(v) >> 23) & 0xff) - 127;
    float scale = ldexpf(1.0f, e);
    scalars[0] = gw;
    scalars[1] = gb;
    scalars[2] = scale;
    scalars[3] = scale * gw;       // epilogue multiplier
    scalars[4] = 127.0f * scale;   // clip bound (exact)
    scalars[5] = ldexpf(1.0f, -e); // inv_scale (exact power of 2)
    sh_gb = gb;
  }
  __syncthreads();
  float gb = sh_gb;
  for (int i = t; i < 1024; i += 256) {
    float q = rintf(bias[i] / (gb + FEPS));
    q = fminf(fmaxf(q, -1.0f), 1.0f);
    bq[i] = q * gb;
  }
}

// ---------------- pass 3: fused quant + int8 MFMA GEMM ----------------------
// One block per 64 rows, 8 waves, 512 blocks (2 blocks/CU co-resident: one
// block's phase-A x reads overlap the other's phase-B MFMAs).
// Phase A: quantize the 64x1024 fp32 x-panel into LDS (fragment-tiled int8,
// 64 KB), one barrier. Phase B: barrier-free; wave wv owns all 64 rows x
// cols (np*512 + wv*64): 16 MFMA per 4 B-loads; every (np,wv) slice unique
// -> block wq traffic exactly 1 MB (512 MB device-wide).
// VGPR budget: acc[4][4]=64 + a[4]=16 + b[4]=16 + addr ~= 112 <= 128 cap
// from __launch_bounds__(512, 4)  (4 waves/EU -> 2 blocks/CU).
__launch_bounds__(512, 4)
__global__ void k_megagemm(const float* __restrict__ x, const unsigned char* __restrict__ wq,
                           const float* __restrict__ scalars, const float* __restrict__ bq,
                           float* __restrict__ out) {
  __shared__ __align__(16) unsigned char Alds[65536];   // 64 tiles x 1KB

  const int tid = threadIdx.x;
  const int lane = tid & 63;
  const int wv = tid >> 6;          // 0..7
  const int mtile = blockIdx.x;     // 0..511 (64-row panel)
  const float qs = scalars[4], inv = scalars[5];

  // ---- Phase A: quantize 8 tiles per wave into LDS ----
  #pragma unroll
  for (int i = 0; i < 8; ++i) {
    const int tile = wv * 8 + i;    // 0..63
    const int mb = tile >> 4;       // 0..3
    const int kt = tile & 15;
    const float4* src = (const float4*)(x + (size_t)(mtile * 64 + mb * 16 + (lane >> 2)) * Kdim
                                          + kt * 64 + (lane & 3) * 16);
    unsigned o[4];
    #pragma unroll
    for (int v = 0; v < 4; ++v) {
      float4 f = src[v];
      int a = (int)rintf(fminf(fmaxf(f.x, -qs), qs) * inv);
      int b = (int)rintf(fminf(fmaxf(f.y, -qs), qs) * inv);
      int c = (int)rintf(fminf(fmaxf(f.z, -qs), qs) * inv);
      int d = (int)rintf(fminf(fmaxf(f.w, -qs), qs) * inv);
      o[v] = (unsigned)(a & 0xff) | ((unsigned)(b & 0xff) << 8) |
             ((unsigned)(c & 0xff) << 16) | ((unsigned)(d & 0xff) << 24);
    }
    uint4 pk; pk.x = o[0]; pk.y = o[1]; pk.z = o[2]; pk.w = o[3];
    const int lp = (lane >> 2) | ((lane & 3) << 4);   // fragment lane
    *(uint4*)(Alds + (size_t)tile * 1024 + lp * 16) = pk;
  }
  __syncthreads();   // the only barrier; Alds is read-only below

  // ---- Phase B: GEMM, 64 rows x 64 cols per wave ----
  const float sg = scalars[3];
  const unsigned char* Aw = Alds + lane * 16;

  #pragma unroll
  for (int np = 0; np < 2; ++np) {
    int4v acc[4][4];
    #pragma unroll
    for (int i = 0; i < 4; ++i)
      #pragma unroll
      for (int j = 0; j < 4; ++j)
        acc[i][j] = (int4v){0, 0, 0, 0};

    const unsigned char* Bb = wq + ((size_t)(np * 32 + wv * 4) * 16) * 1024 + lane * 16;

    #pragma unroll
    for (int kt = 0; kt < 16; ++kt) {
      int4v b0 = *(const int4v*)(Bb + (size_t)(0 * 16 + kt) * 1024);
      int4v b1 = *(const int4v*)(Bb + (size_t)(1 * 16 + kt) * 1024);
      int4v b2 = *(const int4v*)(Bb + (size_t)(2 * 16 + kt) * 1024);
      int4v b3 = *(const int4v*)(Bb + (size_t)(3 * 16 + kt) * 1024);
      int4v a0 = *(const int4v*)(Aw + (size_t)(0 * 16 + kt) * 1024);
      int4v a1 = *(const int4v*)(Aw + (size_t)(1 * 16 + kt) * 1024);
      int4v a2 = *(const int4v*)(Aw + (size_t)(2 * 16 + kt) * 1024);
      int4v a3 = *(const int4v*)(Aw + (size_t)(3 * 16 + kt) * 1024);
      acc[0][0] = __builtin_amdgcn_mfma_i32_16x16x64_i8(a0, b0, acc[0][0], 0, 0, 0);
      acc[0][1] = __builtin_amdgcn_mfma_i32_16x16x64_i8(a0, b1, acc[0][1], 0, 0, 0);
      acc[0][2] = __builtin_amdgcn_mfma_i32_16x16x64_i8(a0, b2, acc[0][2], 0, 0, 0);
      acc[0][3] = __builtin_amdgcn_mfma_i32_16x16x64_i8(a0, b3, acc[0][3], 0, 0, 0);
      acc[1][0] = __builtin_amdgcn_mfma_i32_16x16x64_i8(a1, b0, acc[1][0], 0, 0, 0);
      acc[1][1] = __builtin_amdgcn_mfma_i32_16x16x64_i8(a1, b1, acc[1][1], 0, 0, 0);
      acc[1][2] = __builtin_amdgcn_mfma_i32_16x16x64_i8(a1, b2, acc[1][2], 0, 0, 0);
      acc[1][3] = __builtin_amdgcn_mfma_i32_16x16x64_i8(a1, b3, acc[1][3], 0, 0, 0);
      acc[2][0] = __builtin_amdgcn_mfma_i32_16x16x64_i8(a2, b0, acc[2][0], 0, 0, 0);
      acc[2][1] = __builtin_amdgcn_mfma_i32_16x16x64_i8(a2, b1, acc[2][1], 0, 0, 0);
      acc[2][2] = __builtin_amdgcn_mfma_i32_16x16x64_i8(a2, b2, acc[2][2], 0, 0, 0);
      acc[2][3] = __builtin_amdgcn_mfma_i32_16x16x64_i8(a2, b3, acc[2][3], 0, 0, 0);
      acc[3][0] = __builtin_amdgcn_mfma_i32_16x16x64_i8(a3, b0, acc[3][0], 0, 0, 0);
      acc[3][1] = __builtin_amdgcn_mfma_i32_16x16x64_i8(a3, b1, acc[3][1], 0, 0, 0);
      acc[3][2] = __builtin_amdgcn_mfma_i32_16x16x64_i8(a3, b2, acc[3][2], 0, 0, 0);
      acc[3][3] = __builtin_amdgcn_mfma_i32_16x16x64_i8(a3, b3, acc[3][3], 0, 0, 0);
    }

    // epilogue for this column half (writes overlap next half's compute)
    #pragma unroll
    for (int ni = 0; ni < 4; ++ni) {
      const int col = np * 512 + wv * 64 + ni * 16 + (lane & 15);
      const float bb = bq[col];
      #pragma unroll
      for (int mi = 0; mi < 4; ++mi) {
        const int rowb = mtile * 64 + mi * 16 + (lane >> 4) * 4;
        #pragma unroll
        for (int r = 0; r < 4; ++r)
          out[(size_t)(rowb + r) * Ndim + col] = (float)acc[mi][ni][r] * sg + bb;
      }
    }
  }
}

extern "C" void kernel_launch(void* const* d_in, const int* in_sizes, int n_in,
                              void* d_out, int out_size, void* d_ws, size_t ws_size,
                              hipStream_t stream) {
  const float* x = (const float*)d_in[0];
  const float* weight = (const float*)d_in[1];
  const float* bias = (const float*)d_in[2];
  float* out = (float*)d_out;

  if (ws_size < WS_NEED) return;

  char* ws = (char*)d_ws;
  float* scalars = (float*)ws;
  float* partials = (float*)(ws + 1024);
  unsigned* pmax = (unsigned*)(ws + 4096);
  float* bq = (float*)(ws + 16384);
  unsigned char* wq = (unsigned char*)(ws + WQ_OFF);

  k_pre<<<2304, 256, 0, stream>>>((const uint4*)x, (const float4*)weight, pmax, partials);
  k_finalize2<<<256, 256, 0, stream>>>(bias, weight, partials, pmax, scalars, bq, wq);
  k_megagemm<<<512, 512, 0, stream>>>(x, wq, scalars, bq, out);
}

// Round 9
// 102.871 us; speedup vs baseline: 1.2541x; 1.0825x over previous
//
#include <hip/hip_runtime.h>

typedef __attribute__((ext_vector_type(4))) int int4v;

constexpr int Mdim = 32768;   // 8*4096
constexpr int Kdim = 1024;
constexpr int Ndim = 1024;
constexpr float FEPS = 1e-8f;

// ---------------- ws layout (bytes) ----------------
// 0      : float scalars[8]  {gamma_w, gamma_b, scale, sg, qs, inv_scale}
// 1024   : float partials[256]   (|W| partial sums)
// 4096   : unsigned pmax[2048]   (per-block |x| max bits)
// 16384  : float bq[1024]
// 32768  : int8 wq (1 MB)  -- TILED: tile t=(nb*16+kt) is 1KB; byte l*16 of tile t
//                             holds W[nb*16 + (l&15)][kt*64 + (l>>4)*16 .. +15]
constexpr size_t WQ_OFF = 32768;
constexpr size_t WS_NEED = WQ_OFF + (size_t)Ndim * Kdim;

__device__ __forceinline__ void gload16(const void* g, void* l) {
  __builtin_amdgcn_global_load_lds(
      (const __attribute__((address_space(1))) unsigned int*)g,
      (__attribute__((address_space(3))) unsigned int*)l, 16, 0, 0);
}

// ---------------- pass 1 (merged): |x| absmax partials + |W| sum partials ----
__global__ void k_pre(const uint4* __restrict__ xv, const float4* __restrict__ wv,
                      unsigned* __restrict__ pmax, float* __restrict__ partials) {
  const int tid = threadIdx.x;
  if (blockIdx.x < 2048) {
    int i0 = blockIdx.x * 256 + tid;
    const int stride = 2048 * 256;
    const int n4 = Mdim * Kdim / 4;
    unsigned m = 0u;
    for (int i = i0; i < n4; i += stride) {
      uint4 v = xv[i];
      m = max(m, v.x & 0x7fffffffu);
      m = max(m, v.y & 0x7fffffffu);
      m = max(m, v.z & 0x7fffffffu);
      m = max(m, v.w & 0x7fffffffu);
    }
    #pragma unroll
    for (int off = 32; off > 0; off >>= 1)
      m = max(m, (unsigned)__shfl_down((int)m, off, 64));
    __shared__ unsigned red[4];
    if ((tid & 63) == 0) red[tid >> 6] = m;
    __syncthreads();
    if (tid == 0)
      pmax[blockIdx.x] = max(max(red[0], red[1]), max(red[2], red[3]));
  } else {
    int wb = blockIdx.x - 2048;
    float s = 0.f;
    const int stride = 256 * 256;
    const int n4 = Ndim * Kdim / 4;
    for (int i = wb * 256 + tid; i < n4; i += stride) {
      float4 v = wv[i];
      s += fabsf(v.x) + fabsf(v.y) + fabsf(v.z) + fabsf(v.w);
    }
    __shared__ float red[256];
    red[tid] = s;
    __syncthreads();
    for (int h = 128; h > 0; h >>= 1) {
      if (tid < h) red[tid] += red[tid + h];
      __syncthreads();
    }
    if (tid == 0) partials[wb] = red[0];
  }
}

// ---------------- pass 2: scalars + bias quant + W quant (256 blocks) --------
__global__ void k_finalize2(const float* __restrict__ bias, const float* __restrict__ w,
                            const float* __restrict__ partials, const unsigned* __restrict__ pmax,
                            float* __restrict__ scalars, float* __restrict__ bq,
                            unsigned char* __restrict__ wq) {
  __shared__ float red[256];
  const int t = threadIdx.x;
  const int b = blockIdx.x;

  red[t] = partials[t];
  __syncthreads();
  for (int h = 128; h > 0; h >>= 1) {
    if (t < h) red[t] += red[t + h];
    __syncthreads();
  }
  const float gw = red[0] / (1024.0f * 1024.0f);
  __syncthreads();
  const float inv_g = gw + FEPS;

  {
    const int tile = b * 4 + (t >> 6);   // 0..1023
    const int nb = tile >> 4;
    const int kt = tile & 15;
    const int l = t & 63;
    const float4* src = (const float4*)(w + (size_t)(nb * 16 + (l >> 2)) * Kdim + kt * 64 + (l & 3) * 16);
    unsigned o[4];
    #pragma unroll
    for (int v = 0; v < 4; ++v) {
      float4 f = src[v];
      int a  = (int)rintf(fminf(fmaxf(f.x / inv_g, -1.f), 1.f));
      int bb = (int)rintf(fminf(fmaxf(f.y / inv_g, -1.f), 1.f));
      int cc = (int)rintf(fminf(fmaxf(f.z / inv_g, -1.f), 1.f));
      int dd = (int)rintf(fminf(fmaxf(f.w / inv_g, -1.f), 1.f));
      o[v] = (unsigned)(a & 0xff) | ((unsigned)(bb & 0xff) << 8) |
             ((unsigned)(cc & 0xff) << 16) | ((unsigned)(dd & 0xff) << 24);
    }
    uint4 pk; pk.x = o[0]; pk.y = o[1]; pk.z = o[2]; pk.w = o[3];
    const int lp = (l >> 2) | ((l & 3) << 4);   // fragment lane
    *(uint4*)(wq + (size_t)tile * 1024 + lp * 16) = pk;
  }

  if (b != 0) return;

  __shared__ unsigned redu[256];
  __shared__ float sh_gb;
  unsigned m = 0u;
  #pragma unroll
  for (int i = 0; i < 8; ++i) m = max(m, pmax[t + 256 * i]);
  redu[t] = m;
  float s = fabsf(bias[t]) + fabsf(bias[t + 256]) + fabsf(bias[t + 512]) + fabsf(bias[t + 768]);
  red[t] = s;
  __syncthreads();
  for (int h = 128; h > 0; h >>= 1) {
    if (t < h) {
      red[t] += red[t + h];
      redu[t] = max(redu[t], redu[t + h]);
    }
    __syncthreads();
  }
  if (t == 0) {
    float gb = red[0] / 1024.0f;
    float maxval = __uint_as_float(redu[0]);
    float v = maxval / 127.0f + FEPS;
    int e = (int)((__float_as_uint(v) >> 23) & 0xff) - 127;
    float scale = ldexpf(1.0f, e);
    scalars[0] = gw;
    scalars[1] = gb;
    scalars[2] = scale;
    scalars[3] = scale * gw;       // epilogue multiplier
    scalars[4] = 127.0f * scale;   // clip bound (exact)
    scalars[5] = ldexpf(1.0f, -e); // inv_scale (exact power of 2)
    sh_gb = gb;
  }
  __syncthreads();
  float gb = sh_gb;
  for (int i = t; i < 1024; i += 256) {
    float q = rintf(bias[i] / (gb + FEPS));
    q = fminf(fmaxf(q, -1.0f), 1.0f);
    bq[i] = q * gb;
  }
}

// ---------------- pass 3: fused quant + int8 MFMA GEMM ----------------------
// 512 blocks x 512 threads (8 waves), 80 KB LDS -> 2 blocks/CU.
// Phase A: quantize the block's 64x1024 fp32 x-panel into LDS (64 KB,
// fragment-tiled int8), one __syncthreads.
// Phase B: 128 steps (np 0..7 cols x kt 0..15). Per step: counted vmcnt ->
// raw s_barrier -> async-stage next 8KB B-panel via global_load_lds (zero
// VGPR cost) -> 4x ds_read_b128 (conflict-free) -> 4 MFMA in setprio.
// Wave (wr=wv>>2, wc=wv&3) owns rows wr*32, cols np*128+wc*32. acc[2][2]=16
// AGPR; arch VGPRs stay low so loads pipeline. Epilogue stores per np are
// skipped by vmcnt(16) at the next np's first step (stores drain lazily).
__launch_bounds__(512, 4)
__global__ void k_megagemm(const float* __restrict__ x, const unsigned char* __restrict__ wq,
                           const float* __restrict__ scalars, const float* __restrict__ bq,
                           float* __restrict__ out) {
  __shared__ __align__(16) unsigned char lds[81920];   // A 64KB | B 2x8KB
  unsigned char* Alds = lds;
  unsigned char* Bbuf = lds + 65536;

  const int tid = threadIdx.x;
  const int lane = tid & 63;
  const int wv = tid >> 6;          // 0..7
  const int mtile = blockIdx.x;     // 0..511 (64-row panel)
  const float qs = scalars[4], inv = scalars[5];

  // ---- Phase A: quantize 8 tiles per wave into LDS ----
  #pragma unroll
  for (int i = 0; i < 8; ++i) {
    const int tile = wv * 8 + i;    // 0..63 = mb*16 + kt
    const int mb = tile >> 4;
    const int kt = tile & 15;
    const float4* src = (const float4*)(x + (size_t)(mtile * 64 + mb * 16 + (lane >> 2)) * Kdim
                                          + kt * 64 + (lane & 3) * 16);
    unsigned o[4];
    #pragma unroll
    for (int v = 0; v < 4; ++v) {
      float4 f = src[v];
      int a = (int)rintf(fminf(fmaxf(f.x, -qs), qs) * inv);
      int b = (int)rintf(fminf(fmaxf(f.y, -qs), qs) * inv);
      int c = (int)rintf(fminf(fmaxf(f.z, -qs), qs) * inv);
      int d = (int)rintf(fminf(fmaxf(f.w, -qs), qs) * inv);
      o[v] = (unsigned)(a & 0xff) | ((unsigned)(b & 0xff) << 8) |
             ((unsigned)(c & 0xff) << 16) | ((unsigned)(d & 0xff) << 24);
    }
    uint4 pk; pk.x = o[0]; pk.y = o[1]; pk.z = o[2]; pk.w = o[3];
    const int lp = (lane >> 2) | ((lane & 3) << 4);   // fragment lane
    *(uint4*)(Alds + (size_t)tile * 1024 + lp * 16) = pk;
  }
  __syncthreads();   // Alds complete & read-only hereafter

  // ---- Phase B ----
  const int wr = wv >> 2;           // 0..1 : rows wr*32
  const int wc = wv & 3;            // 0..3 : cols wc*32 within the np group
  const float sg = scalars[3];
  const unsigned char* A0 = Alds + ((size_t)(wr * 2 + 0) * 16) * 1024 + lane * 16;
  const unsigned char* A1 = Alds + ((size_t)(wr * 2 + 1) * 16) * 1024 + lane * 16;

  // stage helper: B tiles for (np,kt) are {(np*8+j)*16+kt}, wave wv stages j=wv
#define STAGEB(np_, kt_) \
    gload16(wq + ((size_t)(((np_) * 8 + wv) * 16 + (kt_))) * 1024 + lane * 16, \
            Bbuf + (((kt_) & 1) * 8192) + wv * 1024 + lane * 16)

  STAGEB(0, 0);   // prologue

  #pragma unroll 1
  for (int np = 0; np < 8; ++np) {
    int4v acc[2][2];
    #pragma unroll
    for (int i = 0; i < 2; ++i)
      #pragma unroll
      for (int j = 0; j < 2; ++j)
        acc[i][j] = (int4v){0, 0, 0, 0};

    #pragma unroll
    for (int kt = 0; kt < 16; ++kt) {
      if (kt == 0) {
        if (np == 0) { asm volatile("s_waitcnt vmcnt(0)" ::: "memory"); }
        else         { asm volatile("s_waitcnt vmcnt(16)" ::: "memory"); }  // skip fresh epilogue stores
      } else         { asm volatile("s_waitcnt vmcnt(0)" ::: "memory"); }
      __builtin_amdgcn_s_barrier();
      asm volatile("" ::: "memory");

      // async-stage next step's B panel (safe: buf last read 2 steps ago)
      if (kt < 15) { STAGEB(np, kt + 1); }
      else if (np < 7) { STAGEB(np + 1, 0); }

      const unsigned char* bb = Bbuf + ((kt & 1) * 8192) + (size_t)(wc * 2) * 1024 + lane * 16;
      int4v b0 = *(const int4v*)(bb);
      int4v b1 = *(const int4v*)(bb + 1024);
      int4v a0 = *(const int4v*)(A0 + (size_t)kt * 1024);
      int4v a1 = *(const int4v*)(A1 + (size_t)kt * 1024);
      __builtin_amdgcn_s_setprio(1);
      acc[0][0] = __builtin_amdgcn_mfma_i32_16x16x64_i8(a0, b0, acc[0][0], 0, 0, 0);
      acc[0][1] = __builtin_amdgcn_mfma_i32_16x16x64_i8(a0, b1, acc[0][1], 0, 0, 0);
      acc[1][0] = __builtin_amdgcn_mfma_i32_16x16x64_i8(a1, b0, acc[1][0], 0, 0, 0);
      acc[1][1] = __builtin_amdgcn_mfma_i32_16x16x64_i8(a1, b1, acc[1][1], 0, 0, 0);
      __builtin_amdgcn_s_setprio(0);
    }

    // epilogue for this 128-col group (stores drain lazily under next np)
    #pragma unroll
    for (int nj = 0; nj < 2; ++nj) {
      const int col = np * 128 + (wc * 2 + nj) * 16 + (lane & 15);
      const float bb = bq[col];
      #pragma unroll
      for (int mi = 0; mi < 2; ++mi) {
        const int rowb = mtile * 64 + wr * 32 + mi * 16 + (lane >> 4) * 4;
        #pragma unroll
        for (int r = 0; r < 4; ++r)
          out[(size_t)(rowb + r) * Ndim + col] = (float)acc[mi][nj][r] * sg + bb;
      }
    }
  }
#undef STAGEB
}

extern "C" void kernel_launch(void* const* d_in, const int* in_sizes, int n_in,
                              void* d_out, int out_size, void* d_ws, size_t ws_size,
                              hipStream_t stream) {
  const float* x = (const float*)d_in[0];
  const float* weight = (const float*)d_in[1];
  const float* bias = (const float*)d_in[2];
  float* out = (float*)d_out;

  if (ws_size < WS_NEED) return;

  char* ws = (char*)d_ws;
  float* scalars = (float*)ws;
  float* partials = (float*)(ws + 1024);
  unsigned* pmax = (unsigned*)(ws + 4096);
  float* bq = (float*)(ws + 16384);
  unsigned char* wq = (unsigned char*)(ws + WQ_OFF);

  k_pre<<<2304, 256, 0, stream>>>((const uint4*)x, (const float4*)weight, pmax, partials);
  k_finalize2<<<256, 256, 0, stream>>>(bias, weight, partials, pmax, scalars, bq, wq);
  k_megagemm<<<512, 512, 0, stream>>>(x, wq, scalars, bq, out);
}